// Round 1
// baseline (152.737 us; speedup 1.0000x reference)
//
#include <hip/hip_runtime.h>
#include <math.h>

// ---------------------------------------------------------------------------
// LowRankLoss: rank(channel-mean(raw)) vs rank(channel-mean(rect)),
// margin-ranking loss, size-averaged.  Rank is scale-invariant, so we skip
// the /C mean scaling and the row-norm normalization and compute the rank of
// the channel-SUM matrix directly via Gaussian elimination with pivoting.
// ---------------------------------------------------------------------------

#define N_BATCH 128
#define C_CH    256
#define H_DIM   32
#define W_DIM   64
#define HW      (H_DIM * W_DIM)      // 2048
#define HW4     (HW / 4)             // 512 float4 per (n) plane row

// K1: channel sum.  One float4 output per thread.
// Grid: 2 inputs * 128 batches * 512 float4 = 131072 threads.
__global__ __launch_bounds__(256) void channel_sum_kernel(
    const float* __restrict__ raw, const float* __restrict__ rect,
    float* __restrict__ m /* [2][128][2048] */)
{
    int v = blockIdx.x * blockDim.x + threadIdx.x;   // 0 .. 131071
    int input = v >> 16;            // /65536
    int rem   = v & 0xFFFF;
    int n     = rem >> 9;           // /512
    int hw4   = rem & 511;

    const float4* src = (const float4*)(input ? rect : raw);
    // row (n,c) = 512 float4
    const float4* p = src + (size_t)(n * C_CH) * HW4 + hw4;

    float4 acc = make_float4(0.f, 0.f, 0.f, 0.f);
#pragma unroll 4
    for (int c = 0; c < C_CH; ++c) {
        float4 x = p[(size_t)c * HW4];
        acc.x += x.x; acc.y += x.y; acc.z += x.z; acc.w += x.w;
    }
    float4* dst = (float4*)m;
    dst[(size_t)v] = acc;
}

// K2: rank of one 32x64 matrix per block (64 threads) via Gaussian
// elimination with row pivoting.  rank = number of nonzero pivots.
__global__ __launch_bounds__(64) void rank_kernel(
    const float* __restrict__ m, float* __restrict__ ranks)
{
    __shared__ float A[H_DIM][W_DIM + 1];   // +1 pad
    __shared__ float f[H_DIM];
    __shared__ int   s_piv;

    int mat = blockIdx.x;               // 0..255
    int t   = threadIdx.x;              // 0..63 = column owner
    const float* src = m + (size_t)mat * HW;

    for (int i = 0; i < H_DIM; ++i) A[i][t] = src[i * W_DIM + t];
    __syncthreads();

    int r = 0;  // uniform across threads
    for (int c = 0; c < W_DIM && r < H_DIM; ++c) {
        if (t == 0) {
            int p = r; float best = fabsf(A[r][c]);
            for (int i = r + 1; i < H_DIM; ++i) {
                float av = fabsf(A[i][c]);
                if (av > best) { best = av; p = i; }
            }
            s_piv = (best > 0.0f) ? p : -1;
        }
        __syncthreads();
        int p = s_piv;
        if (p >= 0) {
            if (p != r) {  // swap rows r,p (parallel over columns)
                float tmp = A[r][t]; A[r][t] = A[p][t]; A[p][t] = tmp;
            }
            __syncthreads();
            if (t > r && t < H_DIM) f[t] = A[t][c] / A[r][c];
            __syncthreads();
            if (t >= c) {
                float arj = A[r][t];
                for (int i = r + 1; i < H_DIM; ++i) A[i][t] -= f[i] * arj;
            }
            ++r;
        }
        __syncthreads();
    }
    if (t == 0) ranks[mat] = (float)r;
}

// K3: loss = sum_n max(0, -(rank1[n]-rank2[n])) / N   (y=1, margin=0)
__global__ __launch_bounds__(128) void loss_kernel(
    const float* __restrict__ ranks, float* __restrict__ out)
{
    __shared__ float red[128];
    int t = threadIdx.x;
    float r1 = ranks[t];              // raw
    float r2 = ranks[N_BATCH + t];    // rectified
    red[t] = fmaxf(0.0f, -(r1 - r2));
    __syncthreads();
    for (int s = 64; s > 0; s >>= 1) {
        if (t < s) red[t] += red[t + s];
        __syncthreads();
    }
    if (t == 0) out[0] = red[0] / (float)N_BATCH;
}

extern "C" void kernel_launch(void* const* d_in, const int* in_sizes, int n_in,
                              void* d_out, int out_size, void* d_ws, size_t ws_size,
                              hipStream_t stream)
{
    const float* raw  = (const float*)d_in[0];
    const float* rect = (const float*)d_in[1];
    float* out = (float*)d_out;

    // ws layout: m[2][128][2048] floats (2 MB), then ranks[256] floats
    float* m     = (float*)d_ws;
    float* ranks = m + 2 * N_BATCH * HW;

    // K1: 2*128*512 float4 outputs = 131072 threads
    channel_sum_kernel<<<131072 / 256, 256, 0, stream>>>(raw, rect, m);
    // K2: one block per matrix
    rank_kernel<<<2 * N_BATCH, 64, 0, stream>>>(m, ranks);
    // K3: final reduction
    loss_kernel<<<1, 128, 0, stream>>>(ranks, out);
}

// Round 2
// 144.980 us; speedup vs baseline: 1.0535x; 1.0535x over previous
//
#include <hip/hip_runtime.h>
#include <math.h>

// ---------------------------------------------------------------------------
// LowRankLoss: rank(channel-mean(raw)) vs rank(channel-mean(rect)),
// margin-ranking loss, size-averaged.  Rank is scale-invariant, so we skip
// the /C mean scaling and row-norm normalization and compute the rank of the
// channel-SUM matrix via Gaussian elimination with partial pivoting.
// ---------------------------------------------------------------------------

#define N_BATCH 128
#define C_CH    256
#define H_DIM   32
#define W_DIM   64
#define HW      (H_DIM * W_DIM)      // 2048
#define HW4     (HW / 4)             // 512 float4 per (n) plane
#define PLANE4  (2 * N_BATCH * HW4)  // 131072 float4 outputs total

// K1: partial channel sum.  KCT chunks of C/KCT channels; one float4 out
// per thread per chunk.  part layout: [KCT][2][128][512] float4.
template <int KCT>
__global__ __launch_bounds__(256) void channel_sum_part(
    const float* __restrict__ raw, const float* __restrict__ rect,
    float* __restrict__ part)
{
    int v = blockIdx.x * blockDim.x + threadIdx.x;   // 0 .. PLANE4*KCT-1
    int k    = v >> 17;             // chunk (PLANE4 = 1<<17)
    int rem  = v & (PLANE4 - 1);
    int input = rem >> 16;
    int rem2  = rem & 0xFFFF;
    int n     = rem2 >> 9;
    int hw4   = rem2 & 511;

    const int CPK = C_CH / KCT;
    const float4* src = (const float4*)(input ? rect : raw);
    const float4* p = src + ((size_t)n * C_CH + (size_t)k * CPK) * HW4 + hw4;

    float4 acc = make_float4(0.f, 0.f, 0.f, 0.f);
#pragma unroll 8
    for (int c = 0; c < CPK; ++c) {
        float4 x = p[(size_t)c * HW4];
        acc.x += x.x; acc.y += x.y; acc.z += x.z; acc.w += x.w;
    }
    ((float4*)part)[(size_t)v] = acc;
}

// K1b: reduce KCT partials in place (chunk 0 slot becomes the final sum).
template <int KCT>
__global__ __launch_bounds__(256) void channel_sum_reduce(float* __restrict__ part)
{
    int v = blockIdx.x * blockDim.x + threadIdx.x;   // 0 .. PLANE4-1
    float4* p = (float4*)part;
    float4 a = p[v];
#pragma unroll
    for (int k = 1; k < KCT; ++k) {
        float4 x = p[(size_t)k * PLANE4 + v];
        a.x += x.x; a.y += x.y; a.z += x.z; a.w += x.w;
    }
    p[v] = a;
}

// K2: rank of one 32x64 matrix per single-wave block.  Register-resident GE
// with partial pivoting; lane t owns column t.  All register arrays are
// statically indexed (runtime pivot handled by unrolled cndmask select).
__global__ __launch_bounds__(64) void rank_kernel(
    const float* __restrict__ m, float* __restrict__ ranks)
{
    int mat = blockIdx.x;               // 0..255
    int t   = threadIdx.x;              // 0..63 = column owner
    const float* src = m + (size_t)mat * HW;

    float a[H_DIM];
#pragma unroll
    for (int i = 0; i < H_DIM; ++i) a[i] = src[i * W_DIM + t];

    unsigned used = 0;                  // bitmask of consumed pivot rows
    int rank = 0;
    for (int c = 0; c < W_DIM; ++c) {
        // broadcast column c to all lanes (values are wave-uniform after this)
        float v[H_DIM];
#pragma unroll
        for (int i = 0; i < H_DIM; ++i) v[i] = __shfl(a[i], c);

        // pivot: argmax |v_i| over unused rows (uniform computation)
        float best = 0.0f; int p = -1;
#pragma unroll
        for (int i = 0; i < H_DIM; ++i) {
            float av = fabsf(v[i]);
            bool cand = (((used >> i) & 1u) == 0u) && (av > best);
            best = cand ? av : best;
            p    = cand ? i  : p;
        }
        if (p >= 0) {
            used |= (1u << p);
            ++rank;
            // select a[p], v[p] with static indexing
            float ap = 0.0f, vp = 1.0f;
#pragma unroll
            for (int i = 0; i < H_DIM; ++i) {
                if (i == p) { ap = a[i]; vp = v[i]; }
            }
            float inv = 1.0f / vp;
#pragma unroll
            for (int i = 0; i < H_DIM; ++i) {
                if (((used >> i) & 1u) == 0u) a[i] -= (v[i] * inv) * ap;
            }
            if (rank == H_DIM) break;
        }
    }
    if (t == 0) ranks[mat] = (float)rank;
}

// K3: loss = sum_n max(0, -(rank1[n]-rank2[n])) / N   (y=1, margin=0)
__global__ __launch_bounds__(128) void loss_kernel(
    const float* __restrict__ ranks, float* __restrict__ out)
{
    __shared__ float red[128];
    int t = threadIdx.x;
    float r1 = ranks[t];              // raw
    float r2 = ranks[N_BATCH + t];    // rectified
    red[t] = fmaxf(0.0f, -(r1 - r2));
    __syncthreads();
    for (int s = 64; s > 0; s >>= 1) {
        if (t < s) red[t] += red[t + s];
        __syncthreads();
    }
    if (t == 0) out[0] = red[0] / (float)N_BATCH;
}

extern "C" void kernel_launch(void* const* d_in, const int* in_sizes, int n_in,
                              void* d_out, int out_size, void* d_ws, size_t ws_size,
                              hipStream_t stream)
{
    const float* raw  = (const float*)d_in[0];
    const float* rect = (const float*)d_in[1];
    float* out = (float*)d_out;

    float* part = (float*)d_ws;

    const size_t need4 = (size_t)4 * PLANE4 * 4 * sizeof(float) + 1024;
    if (ws_size >= need4) {
        // split-K path: 4 chunks -> 2048 blocks (full occupancy), then reduce
        float* ranks = part + (size_t)4 * PLANE4 * 4;
        channel_sum_part<4><<<(PLANE4 * 4) / 256, 256, 0, stream>>>(raw, rect, part);
        channel_sum_reduce<4><<<PLANE4 / 256, 256, 0, stream>>>(part);
        rank_kernel<<<2 * N_BATCH, 64, 0, stream>>>(part, ranks);
        loss_kernel<<<1, 128, 0, stream>>>(ranks, out);
    } else {
        // fallback: single-pass channel sum (2 MB ws)
        float* ranks = part + (size_t)PLANE4 * 4;
        channel_sum_part<1><<<PLANE4 / 256, 256, 0, stream>>>(raw, rect, part);
        rank_kernel<<<2 * N_BATCH, 64, 0, stream>>>(part, ranks);
        loss_kernel<<<1, 128, 0, stream>>>(ranks, out);
    }
}

// Round 3
// 144.273 us; speedup vs baseline: 1.0587x; 1.0049x over previous
//
#include <hip/hip_runtime.h>
#include <math.h>

// ---------------------------------------------------------------------------
// LowRankLoss: rank(channel-mean(raw)) vs rank(channel-mean(rect)),
// margin-ranking loss, size-averaged.  Rank is scale/normalization-invariant,
// so we compute the rank of the channel-SUM matrix via Gaussian elimination
// with partial pivoting.
// ---------------------------------------------------------------------------

#define N_BATCH 128
#define C_CH    256
#define H_DIM   32
#define W_DIM   64
#define HW      (H_DIM * W_DIM)      // 2048 floats per channel row
#define HW4     (HW / 4)             // 512 float4 per channel row

// K1: channel partial sum.  Block b = (plane, chunk): plane = (input,n),
// chunk = one of CHUNKS groups of C/CHUNKS channels.  The block streams a
// CONTIGUOUS (C/CHUNKS)*8KB region: per iteration the 512 threads read one
// 8KB channel row; thread t owns float4 slot t (no LDS, no intra-block
// reduce).  8 named loads per batch for memory-level parallelism.
template <int CHUNKS>
__global__ __launch_bounds__(512) void channel_sum_kernel(
    const float* __restrict__ raw, const float* __restrict__ rect,
    float* __restrict__ part /* [2*128*CHUNKS][2048] floats */)
{
    const int CPR = C_CH / CHUNKS;       // channels per block
    int b     = blockIdx.x;
    int chunk = b % CHUNKS;
    int plane = b / CHUNKS;              // 0..255
    int input = plane >> 7;
    int n     = plane & 127;

    const float* src = input ? rect : raw;
    const float4* p = (const float4*)(src +
        ((size_t)n * C_CH + (size_t)chunk * CPR) * HW) + threadIdx.x;

    float4 acc = make_float4(0.f, 0.f, 0.f, 0.f);
#pragma unroll 1
    for (int cb = 0; cb < CPR; cb += 8) {
        float4 x0 = p[(cb + 0) * HW4];
        float4 x1 = p[(cb + 1) * HW4];
        float4 x2 = p[(cb + 2) * HW4];
        float4 x3 = p[(cb + 3) * HW4];
        float4 x4 = p[(cb + 4) * HW4];
        float4 x5 = p[(cb + 5) * HW4];
        float4 x6 = p[(cb + 6) * HW4];
        float4 x7 = p[(cb + 7) * HW4];
        acc.x += ((x0.x + x1.x) + (x2.x + x3.x)) + ((x4.x + x5.x) + (x6.x + x7.x));
        acc.y += ((x0.y + x1.y) + (x2.y + x3.y)) + ((x4.y + x5.y) + (x6.y + x7.y));
        acc.z += ((x0.z + x1.z) + (x2.z + x3.z)) + ((x4.z + x5.z) + (x6.z + x7.z));
        acc.w += ((x0.w + x1.w) + (x2.w + x3.w)) + ((x4.w + x5.w) + (x6.w + x7.w));
    }
    ((float4*)part)[(size_t)b * 512 + threadIdx.x] = acc;
}

// K2: rank of one 32x64 matrix per single-wave block.  Sums the CHUNKS
// partials inline on load, then register-resident GE with partial pivoting;
// lane t owns column t.  All register arrays statically indexed.
template <int CHUNKS>
__global__ __launch_bounds__(64) void rank_kernel(
    const float* __restrict__ part, float* __restrict__ ranks)
{
    int mat = blockIdx.x;               // 0..255
    int t   = threadIdx.x;              // 0..63 = column owner
    const float* base = part + (size_t)mat * CHUNKS * HW;

    float a[H_DIM];
#pragma unroll
    for (int i = 0; i < H_DIM; ++i) {
        float s = 0.0f;
#pragma unroll
        for (int k = 0; k < CHUNKS; ++k)
            s += base[k * HW + i * W_DIM + t];
        a[i] = s;
    }

    unsigned used = 0;                  // bitmask of consumed pivot rows
    int rank = 0;
    for (int c = 0; c < W_DIM; ++c) {
        // broadcast column c to all lanes (wave-uniform after this)
        float v[H_DIM];
#pragma unroll
        for (int i = 0; i < H_DIM; ++i) v[i] = __shfl(a[i], c);

        // pivot: argmax |v_i| over unused rows (uniform computation)
        float best = 0.0f; int p = -1;
#pragma unroll
        for (int i = 0; i < H_DIM; ++i) {
            float av = fabsf(v[i]);
            bool cand = (((used >> i) & 1u) == 0u) && (av > best);
            best = cand ? av : best;
            p    = cand ? i  : p;
        }
        if (p >= 0) {
            used |= (1u << p);
            ++rank;
            float ap = 0.0f, vp = 1.0f;
#pragma unroll
            for (int i = 0; i < H_DIM; ++i) {
                if (i == p) { ap = a[i]; vp = v[i]; }
            }
            float inv = 1.0f / vp;
#pragma unroll
            for (int i = 0; i < H_DIM; ++i) {
                if (((used >> i) & 1u) == 0u) a[i] -= (v[i] * inv) * ap;
            }
            if (rank == H_DIM) break;
        }
    }
    if (t == 0) ranks[mat] = (float)rank;
}

// K3: loss = sum_n max(0, -(rank1[n]-rank2[n])) / N   (y=1, margin=0)
__global__ __launch_bounds__(128) void loss_kernel(
    const float* __restrict__ ranks, float* __restrict__ out)
{
    __shared__ float red[128];
    int t = threadIdx.x;
    float r1 = ranks[t];              // raw
    float r2 = ranks[N_BATCH + t];    // rectified
    red[t] = fmaxf(0.0f, -(r1 - r2));
    __syncthreads();
    for (int s = 64; s > 0; s >>= 1) {
        if (t < s) red[t] += red[t + s];
        __syncthreads();
    }
    if (t == 0) out[0] = red[0] / (float)N_BATCH;
}

extern "C" void kernel_launch(void* const* d_in, const int* in_sizes, int n_in,
                              void* d_out, int out_size, void* d_ws, size_t ws_size,
                              hipStream_t stream)
{
    const float* raw  = (const float*)d_in[0];
    const float* rect = (const float*)d_in[1];
    float* out = (float*)d_out;
    float* part = (float*)d_ws;

    const size_t need4 = (size_t)2 * N_BATCH * 4 * HW * sizeof(float) + 1024;
    if (ws_size >= need4) {
        // 4 chunks of 64 channels: 1024 blocks, each streams 512KB contiguous
        float* ranks = part + (size_t)2 * N_BATCH * 4 * HW;
        channel_sum_kernel<4><<<2 * N_BATCH * 4, 512, 0, stream>>>(raw, rect, part);
        rank_kernel<4><<<2 * N_BATCH, 64, 0, stream>>>(part, ranks);
        loss_kernel<<<1, 128, 0, stream>>>(ranks, out);
    } else {
        // fallback: 256 blocks, each streams a full 2MB plane
        float* ranks = part + (size_t)2 * N_BATCH * HW;
        channel_sum_kernel<1><<<2 * N_BATCH, 512, 0, stream>>>(raw, rect, part);
        rank_kernel<1><<<2 * N_BATCH, 64, 0, stream>>>(part, ranks);
        loss_kernel<<<1, 128, 0, stream>>>(ranks, out);
    }
}